// Round 1
// baseline (459.832 us; speedup 1.0000x reference)
//
#include <hip/hip_runtime.h>

// Problem constants
constexpr int NB = 32;    // batch
constexpr int NH = 128;   // H
constexpr int NW = 128;   // W
constexpr int NC = 64;    // C
constexpr int MODESX = 32;
constexpr int MODESY = 32;

// ---------------------------------------------------------------------------
// Kernel A: one block per (b, h) with h < MODESX. Full spectral path + conv.
//
// Math (reference fft2/ifft2 act on axes (-2,-1) = (W, C)):
//   X[u,k] = sum_{w,c} x[w,c] e^{-2pi i (u w/128 + k c/64)},  u<32, k<64
//   Y[u,o] = sum_k X[u,k] * (wr+ i wi)[h,u,k,o]
//   spec[w,c] = (1/8192) Re sum_{u<32,o<64} Y[u,o] e^{+2pi i (u w/128 + o c/64)}
//   out = relu(spec + x . conv_w + conv_b)
// Factored cheap order: M1 = F128trunc . x  (32x64 cplx), X = M1 . F64,
//                       S  = Y . G64,        spec = Re(G128 . S)/8192
// ---------------------------------------------------------------------------
__global__ __launch_bounds__(512) void fourier_rows_kernel(
    const float* __restrict__ x,
    const float* __restrict__ w_real,
    const float* __restrict__ w_imag,
    const float* __restrict__ conv_w,
    const float* __restrict__ conv_b,
    float* __restrict__ out)
{
    const int b = blockIdx.x;
    const int h = blockIdx.y;     // < 32
    const int tid = threadIdx.x;  // 0..511

    __shared__ float  sx[NW * NC];        // 32 KB input slice, kept for conv
    __shared__ float2 bufA[MODESX * NC];  // 16 KB: M1, then Y
    __shared__ float2 bufB[MODESX * NC];  // 16 KB: X, then S
    __shared__ float  scw[NC * NC];       // 16 KB conv_w
    __shared__ float  scb[NC];
    __shared__ float2 tw128[128];         // (cos, sin)(2 pi t / 128)
    __shared__ float2 tw64[64];           // (cos, sin)(2 pi t / 64)

    // ---- stage 0: loads ----
    const float* xrow = x + ((size_t)(b * NH + h)) * NW * NC;
    {
        const float4* x4 = (const float4*)xrow;
        float4* sx4 = (float4*)sx;
        #pragma unroll
        for (int i = 0; i < 4; ++i) sx4[tid + i * 512] = x4[tid + i * 512];
        const float4* cw4 = (const float4*)conv_w;
        float4* scw4 = (float4*)scw;
        #pragma unroll
        for (int i = 0; i < 2; ++i) scw4[tid + i * 512] = cw4[tid + i * 512];
        if (tid < NC) scb[tid] = conv_b[tid];
        if (tid < 128) {
            float ang = (float)tid * (6.2831853071795864769f / 128.0f);
            tw128[tid] = make_float2(__cosf(ang) * 0.0f + cosf(ang), sinf(ang));
        }
        if (tid < 64) {
            float ang = (float)tid * (6.2831853071795864769f / 64.0f);
            tw64[tid] = make_float2(cosf(ang), sinf(ang));
        }
    }
    __syncthreads();

    // ---- stage 1: M1[u,c] = sum_w e^{-2pi i u w/128} x[w,c]  (real input) ----
    #pragma unroll
    for (int j = 0; j < 4; ++j) {
        int idx = tid + j * 512;           // 0..2047
        int u = idx >> 6, c = idx & 63;
        float re = 0.f, im = 0.f;
        for (int w = 0; w < 128; ++w) {
            float a = sx[w * 64 + c];      // lanes: consecutive c -> no conflict
            float2 t = tw128[(u * w) & 127]; // wave-uniform -> broadcast
            re += a * t.x;
            im -= a * t.y;
        }
        bufA[idx] = make_float2(re, im);   // M1
    }
    __syncthreads();

    // ---- stage 2: X[u,k] = sum_c M1[u,c] e^{-2pi i k c/64} ----
    #pragma unroll
    for (int j = 0; j < 4; ++j) {
        int idx = tid + j * 512;
        int u = idx >> 6, k = idx & 63;
        float re = 0.f, im = 0.f;
        for (int c = 0; c < 64; ++c) {
            float2 m = bufA[u * 64 + c];   // wave-uniform -> broadcast
            float2 t = tw64[(k * c) & 63];
            re += m.x * t.x + m.y * t.y;   // m * (cos - i sin)
            im += m.y * t.x - m.x * t.y;
        }
        bufB[idx] = make_float2(re, im);   // X
    }
    __syncthreads();

    // ---- stage 3: Y[u,o] = sum_k X[u,k] * W[h,u,k,o]  (complex) ----
    #pragma unroll
    for (int j = 0; j < 4; ++j) {
        int idx = tid + j * 512;
        int u = idx >> 6, o = idx & 63;
        const float* wr = w_real + (((size_t)(h * 32 + u)) * 64) * 64 + o;
        const float* wi = w_imag + (((size_t)(h * 32 + u)) * 64) * 64 + o;
        float re = 0.f, im = 0.f;
        for (int k = 0; k < 64; ++k) {
            float2 xv = bufB[u * 64 + k];  // broadcast
            float a = wr[k * 64];          // coalesced over o
            float bb = wi[k * 64];
            re += xv.x * a - xv.y * bb;
            im += xv.x * bb + xv.y * a;
        }
        bufA[idx] = make_float2(re, im);   // Y (reuses M1 region)
    }
    __syncthreads();

    // ---- stage 4: S[u,c] = sum_o Y[u,o] e^{+2pi i o c/64} ----
    #pragma unroll
    for (int j = 0; j < 4; ++j) {
        int idx = tid + j * 512;
        int u = idx >> 6, c = idx & 63;
        float re = 0.f, im = 0.f;
        for (int o = 0; o < 64; ++o) {
            float2 yv = bufA[u * 64 + o];  // broadcast
            float2 t = tw64[(o * c) & 63];
            re += yv.x * t.x - yv.y * t.y; // y * (cos + i sin)
            im += yv.x * t.y + yv.y * t.x;
        }
        bufB[idx] = make_float2(re, im);   // S (reuses X region)
    }
    __syncthreads();

    // ---- stage 5: spec + conv + relu + store ----
    float* orow = out + ((size_t)(b * NH + h)) * NW * NC;
    #pragma unroll
    for (int j = 0; j < 16; ++j) {
        int idx = tid + j * 512;           // 0..8191
        int w = idx >> 6, c = idx & 63;
        float spec = 0.f;
        for (int u = 0; u < 32; ++u) {
            float2 s = bufB[u * 64 + c];   // consecutive c -> no conflict
            float2 t = tw128[(u * w) & 127]; // broadcast
            spec += s.x * t.x - s.y * t.y; // Re(S e^{+i ang})
        }
        float acc = scb[c];
        for (int i = 0; i < 64; ++i)
            acc += sx[w * 64 + i] * scw[i * 64 + c]; // sx broadcast, scw no-conflict
        float v = spec * (1.0f / 8192.0f) + acc;
        orow[idx] = v > 0.f ? v : 0.f;
    }
}

// ---------------------------------------------------------------------------
// Kernel B: rows h >= 32 — local 1x1 conv + relu only (spec part is zero).
// One block per (b, h). 512 threads.
// ---------------------------------------------------------------------------
__global__ __launch_bounds__(512) void local_rows_kernel(
    const float* __restrict__ x,
    const float* __restrict__ conv_w,
    const float* __restrict__ conv_b,
    float* __restrict__ out)
{
    const int b = blockIdx.x;
    const int h = blockIdx.y + MODESX;    // 32..127
    const int tid = threadIdx.x;

    __shared__ float sx[NW * NC];   // 32 KB
    __shared__ float scw[NC * NC];  // 16 KB
    __shared__ float scb[NC];

    const float* xrow = x + ((size_t)(b * NH + h)) * NW * NC;
    {
        const float4* x4 = (const float4*)xrow;
        float4* sx4 = (float4*)sx;
        #pragma unroll
        for (int i = 0; i < 4; ++i) sx4[tid + i * 512] = x4[tid + i * 512];
        const float4* cw4 = (const float4*)conv_w;
        float4* scw4 = (float4*)scw;
        #pragma unroll
        for (int i = 0; i < 2; ++i) scw4[tid + i * 512] = cw4[tid + i * 512];
        if (tid < NC) scb[tid] = conv_b[tid];
    }
    __syncthreads();

    float* orow = out + ((size_t)(b * NH + h)) * NW * NC;
    #pragma unroll
    for (int j = 0; j < 16; ++j) {
        int idx = tid + j * 512;
        int w = idx >> 6, c = idx & 63;
        float acc = scb[c];
        for (int i = 0; i < 64; ++i)
            acc += sx[w * 64 + i] * scw[i * 64 + c];
        orow[idx] = acc > 0.f ? acc : 0.f;
    }
}

extern "C" void kernel_launch(void* const* d_in, const int* in_sizes, int n_in,
                              void* d_out, int out_size, void* d_ws, size_t ws_size,
                              hipStream_t stream) {
    const float* x      = (const float*)d_in[0];
    const float* w_real = (const float*)d_in[1];
    const float* w_imag = (const float*)d_in[2];
    const float* conv_w = (const float*)d_in[3];
    const float* conv_b = (const float*)d_in[4];
    float* out = (float*)d_out;

    fourier_rows_kernel<<<dim3(NB, MODESX), 512, 0, stream>>>(
        x, w_real, w_imag, conv_w, conv_b, out);
    local_rows_kernel<<<dim3(NB, NH - MODESX), 512, 0, stream>>>(
        x, conv_w, conv_b, out);
}

// Round 2
// 85.907 us; speedup vs baseline: 5.3527x; 5.3527x over previous
//
#include <hip/hip_runtime.h>

typedef __attribute__((ext_vector_type(8))) short short8;
typedef __attribute__((ext_vector_type(4))) float f32x4;
typedef unsigned short ushort_t;

#define MFMA(a, b, c) __builtin_amdgcn_mfma_f32_16x16x32_bf16((a), (b), (c), 0, 0, 0)

constexpr int NB = 32, NHt = 128, NWd = 128, NC = 64, MX = 32;
constexpr float TWO_PI = 6.28318530717958647692f;

// workspace layout (needs 65536 + 8,388,608 bytes ~= 8.07 MiB)
constexpr size_t TAB_T1 = 0;      // K1 stage1 A: F128 fwd  [mt2][ks4][lane64][re8,im8] bf16 (16KB)
constexpr size_t TAB_T2 = 16384;  // K1 stage2 B: G64  fwd  [nt4][ks2][lane64][re8,im8]
constexpr size_t TAB_T3 = 32768;  // K3 stage4 B: G64  inv  [nt4][ks2][lane64][re8,im8]
constexpr size_t TAB_T4 = 49152;  // K3 stage5 A: G128 inv  [mt8][lane64][re8,im8]
constexpr size_t XY_OFF = 65536;  // X then Y in-place: bf16 [h32][u32][comp2][b32][k64]

__device__ inline ushort_t f2bf(float f) {
    union { float f; unsigned int u; } v; v.f = f;
    unsigned int r = v.u + 0x7FFFu + ((v.u >> 16) & 1u);   // RTN-even
    return (ushort_t)(r >> 16);
}
__device__ inline float bf2f(ushort_t b) {
    union { unsigned int u; float f; } v; v.u = ((unsigned int)b) << 16;
    return v.f;
}

// ---------------------------------------------------------------------------
// K0: twiddle fragment tables, in exact MFMA A/B lane layout.
// A/B frag: row/col = (lane&15)+16*tile, k = (lane>>4)*8 + j (+32*ks).
// ---------------------------------------------------------------------------
__global__ __launch_bounds__(256) void k0_tables(ushort_t* __restrict__ tabs)
{
    int e = blockIdx.x * 256 + threadIdx.x;   // 0..2047
    int tab = e >> 9, rem = e & 511;
    float re[8], im[8];
    if (tab == 0) {            // F128 fwd: exp(-2pi i u w/128)
        int mt = rem >> 8, ks = (rem >> 6) & 3, l = rem & 63;
        int uu = (l & 15) + 16 * mt, wb = (l >> 4) * 8 + 32 * ks;
        #pragma unroll
        for (int j = 0; j < 8; ++j) {
            float a = (float)((uu * (wb + j)) & 127) * (TWO_PI / 128.f);
            re[j] = cosf(a); im[j] = -sinf(a);
        }
    } else if (tab == 1) {     // G64 fwd: exp(-2pi i k c/64), col=k, k'=c
        int nt = rem >> 7, ks = (rem >> 6) & 1, l = rem & 63;
        int kk = (l & 15) + 16 * nt, cb2 = (l >> 4) * 8 + 32 * ks;
        #pragma unroll
        for (int j = 0; j < 8; ++j) {
            float a = (float)((kk * (cb2 + j)) & 63) * (TWO_PI / 64.f);
            re[j] = cosf(a); im[j] = -sinf(a);
        }
    } else if (tab == 2) {     // G64 inv: exp(+2pi i o c/64), col=c, k'=o
        int nt = rem >> 7, ks = (rem >> 6) & 1, l = rem & 63;
        int cc = (l & 15) + 16 * nt, ob = (l >> 4) * 8 + 32 * ks;
        #pragma unroll
        for (int j = 0; j < 8; ++j) {
            float a = (float)(((ob + j) * cc) & 63) * (TWO_PI / 64.f);
            re[j] = cosf(a); im[j] = sinf(a);
        }
    } else {                   // G128 inv: exp(+2pi i w u/128), row=w, k=u
        int mt = rem >> 6, l = rem & 63;
        int w = (l & 15) + 16 * mt, ub = (l >> 4) * 8;
        #pragma unroll
        for (int j = 0; j < 8; ++j) {
            float a = (float)((w * (ub + j)) & 127) * (TWO_PI / 128.f);
            re[j] = cosf(a); im[j] = sinf(a);
        }
    }
    ushort_t* dst = tabs + (size_t)e * 16;
    #pragma unroll
    for (int j = 0; j < 8; ++j) { dst[j] = f2bf(re[j]); dst[8 + j] = f2bf(im[j]); }
}

// ---------------------------------------------------------------------------
// K1: per (b, h<32). M1 = F128trunc . x  (32x64 cplx), X = M1 . G64fwd.
// Writes X bf16 to ws [h][u][comp][b][k].
// ---------------------------------------------------------------------------
__global__ __launch_bounds__(512) void k1_fwd(
    const float* __restrict__ x, const char* __restrict__ tabs, ushort_t* __restrict__ XY)
{
    const int b = blockIdx.x, h = blockIdx.y;
    const int tid = threadIdx.x, lane = tid & 63, wv = tid >> 6;
    constexpr int SXT  = 0;            // x^T bf16 [c64][w128], stride 272B (17*16)
    constexpr int M1RE = 17408;        // [u32][c64+pad], stride 144B (9*16)
    constexpr int M1IM = 17408 + 4608;
    __shared__ __align__(16) char sm[26624];

    // load + transpose x slice -> sxT[c][w] bf16
    const float* xs = x + ((size_t)(b * NHt + h)) * (NWd * NC);
    #pragma unroll
    for (int i = 0; i < 4; ++i) {
        int w = (tid >> 4) + 32 * i;
        #pragma unroll
        for (int j = 0; j < 4; ++j) {
            int c = (tid & 15) + 16 * j;
            *(ushort_t*)(sm + SXT + c * 272 + w * 2) = f2bf(xs[w * 64 + c]);
        }
    }
    __syncthreads();

    const int mt = wv >> 2, nt = wv & 3;   // tile of the 2x4 grid (u-tiles x c/k-tiles)
    // stage 1: M1[u,c] = sum_w F[u,w] x[w,c]   (A = F table, B = sxT)
    f32x4 m1r = {0.f,0.f,0.f,0.f}, m1i = {0.f,0.f,0.f,0.f};
    #pragma unroll
    for (int ks = 0; ks < 4; ++ks) {
        short8 bfrag = *reinterpret_cast<const short8*>(
            sm + SXT + ((lane & 15) + 16 * nt) * 272 + (lane >> 4) * 16 + 64 * ks);
        const char* t1 = tabs + TAB_T1 + (((mt * 4 + ks) * 64 + lane) * 32);
        short8 are = *reinterpret_cast<const short8*>(t1);
        short8 aim = *reinterpret_cast<const short8*>(t1 + 16);
        m1r = MFMA(are, bfrag, m1r);
        m1i = MFMA(aim, bfrag, m1i);
    }
    #pragma unroll
    for (int r = 0; r < 4; ++r) {
        int u = (lane >> 4) * 4 + r + 16 * mt;
        int c = (lane & 15) + 16 * nt;
        *(ushort_t*)(sm + M1RE + u * 144 + c * 2) = f2bf(m1r[r]);
        *(ushort_t*)(sm + M1IM + u * 144 + c * 2) = f2bf(m1i[r]);
    }
    __syncthreads();

    // stage 2: X[u,k] = sum_c M1[u,c] G64f[c,k]
    f32x4 xP = {0.f,0.f,0.f,0.f}, xQ = {0.f,0.f,0.f,0.f}, xI = {0.f,0.f,0.f,0.f};
    #pragma unroll
    for (int ks = 0; ks < 2; ++ks) {
        short8 are = *reinterpret_cast<const short8*>(
            sm + M1RE + ((lane & 15) + 16 * mt) * 144 + (lane >> 4) * 16 + 64 * ks);
        short8 aim = *reinterpret_cast<const short8*>(
            sm + M1IM + ((lane & 15) + 16 * mt) * 144 + (lane >> 4) * 16 + 64 * ks);
        const char* t2 = tabs + TAB_T2 + (((nt * 2 + ks) * 64 + lane) * 32);
        short8 bre = *reinterpret_cast<const short8*>(t2);
        short8 bim = *reinterpret_cast<const short8*>(t2 + 16);
        xP = MFMA(are, bre, xP);
        xQ = MFMA(aim, bim, xQ);
        xI = MFMA(are, bim, xI);
        xI = MFMA(aim, bre, xI);
    }
    #pragma unroll
    for (int r = 0; r < 4; ++r) {
        int u = (lane >> 4) * 4 + r + 16 * mt;
        int k = (lane & 15) + 16 * nt;
        size_t hu = (size_t)(h * 32 + u);
        XY[((hu * 2 + 0) * 32 + b) * 64 + k] = f2bf(xP[r] - xQ[r]);
        XY[((hu * 2 + 1) * 32 + b) * 64 + k] = f2bf(xI[r]);
    }
}

// ---------------------------------------------------------------------------
// K2: per (h, u). Y[b,o] = sum_k X[b,k] W[h,u,k,o] — b-batched so W is read
// from HBM exactly once. In-place X->Y in ws (staged to LDS first).
// ---------------------------------------------------------------------------
__global__ __launch_bounds__(256) void k2_mix(
    const float* __restrict__ wre, const float* __restrict__ wim, ushort_t* __restrict__ XY)
{
    const int h = blockIdx.x, u = blockIdx.y;
    const int tid = threadIdx.x, lane = tid & 63, wv = tid >> 6;   // 4 waves
    constexpr int XRE = 0, XIM = 4608, WTR = 9216, WTI = 18432;    // strides 144B
    __shared__ __align__(16) char sm[27648];
    const size_t hu = (size_t)(h * 32 + u);

    #pragma unroll
    for (int it = 0; it < 2; ++it) {        // stage X[b][k] (both comps)
        int row = (tid >> 3) + 32 * it;
        int comp = row >> 5, bb = row & 31, k8 = (tid & 7) * 8;
        short8 v = *reinterpret_cast<const short8*>(XY + ((hu * 2 + comp) * 32 + bb) * 64 + k8);
        *reinterpret_cast<short8*>(sm + (comp ? XIM : XRE) + bb * 144 + k8 * 2) = v;
    }
    const float* wr = wre + hu * 4096;      // transpose W -> WT[o][k] bf16
    const float* wi = wim + hu * 4096;
    #pragma unroll
    for (int i = 0; i < 4; ++i) {
        int k = (tid >> 4) + 16 * i;
        #pragma unroll
        for (int j = 0; j < 4; ++j) {
            int o = (tid & 15) + 16 * j;
            *(ushort_t*)(sm + WTR + o * 144 + k * 2) = f2bf(wr[k * 64 + o]);
            *(ushort_t*)(sm + WTI + o * 144 + k * 2) = f2bf(wi[k * 64 + o]);
        }
    }
    __syncthreads();

    const int mt = wv >> 1;
    #pragma unroll
    for (int half = 0; half < 2; ++half) {
        const int nt = (wv & 1) * 2 + half;
        f32x4 yP = {0.f,0.f,0.f,0.f}, yQ = {0.f,0.f,0.f,0.f}, yI = {0.f,0.f,0.f,0.f};
        #pragma unroll
        for (int ks = 0; ks < 2; ++ks) {
            short8 are = *reinterpret_cast<const short8*>(
                sm + XRE + ((lane & 15) + 16 * mt) * 144 + (lane >> 4) * 16 + 64 * ks);
            short8 aim = *reinterpret_cast<const short8*>(
                sm + XIM + ((lane & 15) + 16 * mt) * 144 + (lane >> 4) * 16 + 64 * ks);
            short8 bre = *reinterpret_cast<const short8*>(
                sm + WTR + ((lane & 15) + 16 * nt) * 144 + (lane >> 4) * 16 + 64 * ks);
            short8 bim = *reinterpret_cast<const short8*>(
                sm + WTI + ((lane & 15) + 16 * nt) * 144 + (lane >> 4) * 16 + 64 * ks);
            yP = MFMA(are, bre, yP); yQ = MFMA(aim, bim, yQ);
            yI = MFMA(are, bim, yI); yI = MFMA(aim, bre, yI);
        }
        #pragma unroll
        for (int r = 0; r < 4; ++r) {
            int bb = (lane >> 4) * 4 + r + 16 * mt;
            int o = (lane & 15) + 16 * nt;
            XY[((hu * 2 + 0) * 32 + bb) * 64 + o] = f2bf(yP[r] - yQ[r]);
            XY[((hu * 2 + 1) * 32 + bb) * 64 + o] = f2bf(yI[r]);
        }
    }
}

// ---------------------------------------------------------------------------
// K3: per (b, h in 0..127). h<32: S = Y.G64inv, spec = Re(G128inv.S)/8192.
// All h: conv (x hi/lo split bf16) + bias + relu + store.
// ---------------------------------------------------------------------------
__global__ __launch_bounds__(512) void k3_inv(
    const float* __restrict__ x, const float* __restrict__ cw, const float* __restrict__ cb,
    const char* __restrict__ tabs, const ushort_t* __restrict__ XY, float* __restrict__ out)
{
    const int b = blockIdx.x, h = blockIdx.y;
    const int tid = threadIdx.x, lane = tid & 63, wv = tid >> 6;
    constexpr int ST_RE = 0, ST_IM = 5120;            // S^T [c64][u32+pad], stride 80B
    constexpr int YRE = 10240, YIM = 14848;           // [u32][o64+pad], stride 144B
    constexpr int XHI = 10240, XLO = 28672;           // [w128][c64+pad], stride 144B
    constexpr int CWT = 47104;                        // [o64][i64+pad], stride 144B
    constexpr int SCB = 56320;                        // bias f32[64]
    __shared__ __align__(16) char sm[56576];

    if (h < MX) {
        {   // stage Y -> LDS
            int u = tid >> 4, comp = (tid >> 3) & 1, o8 = (tid & 7) * 8;
            size_t hu = (size_t)(h * 32 + u);
            short8 v = *reinterpret_cast<const short8*>(XY + ((hu * 2 + comp) * 32 + b) * 64 + o8);
            *reinterpret_cast<short8*>(sm + (comp ? YIM : YRE) + u * 144 + o8 * 2) = v;
        }
        __syncthreads();
        // stage 4: S[u,c] = sum_o Y[u,o] G64inv[o,c]; write S transposed [c][u]
        const int mt = wv >> 2, nt = wv & 3;
        f32x4 sP = {0.f,0.f,0.f,0.f}, sQ = {0.f,0.f,0.f,0.f}, sI = {0.f,0.f,0.f,0.f};
        #pragma unroll
        for (int ks = 0; ks < 2; ++ks) {
            short8 are = *reinterpret_cast<const short8*>(
                sm + YRE + ((lane & 15) + 16 * mt) * 144 + (lane >> 4) * 16 + 64 * ks);
            short8 aim = *reinterpret_cast<const short8*>(
                sm + YIM + ((lane & 15) + 16 * mt) * 144 + (lane >> 4) * 16 + 64 * ks);
            const char* t3 = tabs + TAB_T3 + (((nt * 2 + ks) * 64 + lane) * 32);
            short8 bre = *reinterpret_cast<const short8*>(t3);
            short8 bim = *reinterpret_cast<const short8*>(t3 + 16);
            sP = MFMA(are, bre, sP); sQ = MFMA(aim, bim, sQ);
            sI = MFMA(are, bim, sI); sI = MFMA(aim, bre, sI);
        }
        #pragma unroll
        for (int r = 0; r < 4; ++r) {
            int u = (lane >> 4) * 4 + r + 16 * mt;
            int c = (lane & 15) + 16 * nt;
            *(ushort_t*)(sm + ST_RE + c * 80 + u * 2) = f2bf(sP[r] - sQ[r]);
            *(ushort_t*)(sm + ST_IM + c * 80 + u * 2) = f2bf(sI[r]);
        }
    }
    __syncthreads();

    // stage x (hi/lo split), conv_w^T, bias
    const float* xs = x + ((size_t)(b * NHt + h)) * (NWd * NC);
    #pragma unroll
    for (int i = 0; i < 4; ++i) {
        int idx4 = tid + 512 * i;
        int w = idx4 >> 4, c4 = (idx4 & 15) * 4;
        float4 v = *reinterpret_cast<const float4*>(xs + w * 64 + c4);
        ushort_t h0 = f2bf(v.x), h1 = f2bf(v.y), h2 = f2bf(v.z), h3 = f2bf(v.w);
        *(unsigned int*)(sm + XHI + w * 144 + c4 * 2)     = (unsigned)h0 | ((unsigned)h1 << 16);
        *(unsigned int*)(sm + XHI + w * 144 + c4 * 2 + 4) = (unsigned)h2 | ((unsigned)h3 << 16);
        ushort_t l0 = f2bf(v.x - bf2f(h0)), l1 = f2bf(v.y - bf2f(h1));
        ushort_t l2 = f2bf(v.z - bf2f(h2)), l3 = f2bf(v.w - bf2f(h3));
        *(unsigned int*)(sm + XLO + w * 144 + c4 * 2)     = (unsigned)l0 | ((unsigned)l1 << 16);
        *(unsigned int*)(sm + XLO + w * 144 + c4 * 2 + 4) = (unsigned)l2 | ((unsigned)l3 << 16);
    }
    #pragma unroll
    for (int i = 0; i < 2; ++i) {
        int ii = (tid >> 4) + 32 * i;
        #pragma unroll
        for (int j = 0; j < 4; ++j) {
            int o = (tid & 15) + 16 * j;
            *(ushort_t*)(sm + CWT + o * 144 + ii * 2) = f2bf(cw[ii * 64 + o]);
        }
    }
    if (tid < 64) ((float*)(sm + SCB))[tid] = cb[tid];
    __syncthreads();

    short8 gre = {}, gim = {};
    if (h < MX) {
        const char* t4 = tabs + TAB_T4 + ((wv * 64 + lane) * 32);
        gre = *reinterpret_cast<const short8*>(t4);
        gim = *reinterpret_cast<const short8*>(t4 + 16);
    }
    float* orow = out + ((size_t)(b * NHt + h)) * (NWd * NC);
    #pragma unroll
    for (int nt = 0; nt < 4; ++nt) {
        f32x4 acc = {0.f,0.f,0.f,0.f};     // conv accumulator
        #pragma unroll
        for (int ks = 0; ks < 2; ++ks) {
            short8 ah = *reinterpret_cast<const short8*>(
                sm + XHI + ((lane & 15) + 16 * wv) * 144 + (lane >> 4) * 16 + 64 * ks);
            short8 al = *reinterpret_cast<const short8*>(
                sm + XLO + ((lane & 15) + 16 * wv) * 144 + (lane >> 4) * 16 + 64 * ks);
            short8 bw = *reinterpret_cast<const short8*>(
                sm + CWT + ((lane & 15) + 16 * nt) * 144 + (lane >> 4) * 16 + 64 * ks);
            acc = MFMA(ah, bw, acc);
            acc = MFMA(al, bw, acc);
        }
        f32x4 sp = {0.f,0.f,0.f,0.f}, sq = {0.f,0.f,0.f,0.f};
        if (h < MX) {   // stage 5: spec = Re(G128inv . S), K=32 single step
            short8 bre = *reinterpret_cast<const short8*>(
                sm + ST_RE + ((lane & 15) + 16 * nt) * 80 + (lane >> 4) * 16);
            short8 bim = *reinterpret_cast<const short8*>(
                sm + ST_IM + ((lane & 15) + 16 * nt) * 80 + (lane >> 4) * 16);
            sp = MFMA(gre, bre, sp);
            sq = MFMA(gim, bim, sq);
        }
        #pragma unroll
        for (int r = 0; r < 4; ++r) {
            int w = (lane >> 4) * 4 + r + 16 * wv;
            int c = (lane & 15) + 16 * nt;
            float v = acc[r] + ((const float*)(sm + SCB))[c];
            if (h < MX) v += (sp[r] - sq[r]) * (1.0f / 8192.0f);
            orow[w * 64 + c] = fmaxf(v, 0.0f);
        }
    }
}

extern "C" void kernel_launch(void* const* d_in, const int* in_sizes, int n_in,
                              void* d_out, int out_size, void* d_ws, size_t ws_size,
                              hipStream_t stream) {
    const float* x      = (const float*)d_in[0];
    const float* w_real = (const float*)d_in[1];
    const float* w_imag = (const float*)d_in[2];
    const float* conv_w = (const float*)d_in[3];
    const float* conv_b = (const float*)d_in[4];
    float* out = (float*)d_out;

    ushort_t* tabs = (ushort_t*)d_ws;
    ushort_t* XY   = (ushort_t*)((char*)d_ws + XY_OFF);

    k0_tables<<<8, 256, 0, stream>>>(tabs);
    k1_fwd<<<dim3(NB, MX), 512, 0, stream>>>(x, (const char*)d_ws, XY);
    k2_mix<<<dim3(MX, 32), 256, 0, stream>>>(w_real, w_imag, XY);
    k3_inv<<<dim3(NB, NHt), 512, 0, stream>>>(x, conv_w, conv_b,
                                              (const char*)d_ws, XY, out);
}

// Round 3
// 84.563 us; speedup vs baseline: 5.4377x; 1.0159x over previous
//
#include <hip/hip_runtime.h>

typedef __attribute__((ext_vector_type(8))) short short8;
typedef __attribute__((ext_vector_type(4))) float f32x4;
typedef unsigned short ushort_t;

#define MFMA(a, b, c) __builtin_amdgcn_mfma_f32_16x16x32_bf16((a), (b), (c), 0, 0, 0)

constexpr int NB = 32, NHt = 128, NWd = 128, NC = 64, MX = 32;
constexpr float TWO_PI = 6.28318530717958647692f;

// workspace layout (64 KB tables + 8 MiB X/Y buffer)
constexpr size_t TAB_T1 = 0;      // K1 stage1 A: F128 fwd  [mt2][ks4][lane64][re8,im8]
constexpr size_t TAB_T2 = 16384;  // K1 stage2 B: G64  fwd  [nt4][ks2][lane64][re8,im8]
constexpr size_t TAB_T3 = 32768;  // K3 stage4 B: G64  inv  [nt4][ks2][lane64][re8,im8]
constexpr size_t TAB_T4 = 49152;  // K3 stage5 A: G128 inv  [mt8][lane64][re8,im8] (x 1/8192)
constexpr size_t XY_OFF = 65536;  // X then Y in-place: bf16 [h32][u32][comp2][b32][k64]

__device__ inline ushort_t f2bf(float f) {
    union { float f; unsigned int u; } v; v.f = f;
    unsigned int r = v.u + 0x7FFFu + ((v.u >> 16) & 1u);   // RTN-even
    return (ushort_t)(r >> 16);
}

// ---------------------------------------------------------------------------
// K0: twiddle fragment tables in exact MFMA A/B lane layout.
// A/B frag: row/col = (lane&15)+16*tile, k = (lane>>4)*8 + j (+32*ks).
// ---------------------------------------------------------------------------
__global__ __launch_bounds__(256) void k0_tables(ushort_t* __restrict__ tabs)
{
    int e = blockIdx.x * 256 + threadIdx.x;   // 0..2047
    int tab = e >> 9, rem = e & 511;
    float re[8], im[8];
    if (tab == 0) {            // F128 fwd: exp(-2pi i u w/128)
        int mt = rem >> 8, ks = (rem >> 6) & 3, l = rem & 63;
        int uu = (l & 15) + 16 * mt, wb = (l >> 4) * 8 + 32 * ks;
        #pragma unroll
        for (int j = 0; j < 8; ++j) {
            float a = (float)((uu * (wb + j)) & 127) * (TWO_PI / 128.f);
            re[j] = cosf(a); im[j] = -sinf(a);
        }
    } else if (tab == 1) {     // G64 fwd: exp(-2pi i k c/64), col=k, k'=c
        int nt = rem >> 7, ks = (rem >> 6) & 1, l = rem & 63;
        int kk = (l & 15) + 16 * nt, cb2 = (l >> 4) * 8 + 32 * ks;
        #pragma unroll
        for (int j = 0; j < 8; ++j) {
            float a = (float)((kk * (cb2 + j)) & 63) * (TWO_PI / 64.f);
            re[j] = cosf(a); im[j] = -sinf(a);
        }
    } else if (tab == 2) {     // G64 inv: exp(+2pi i o c/64), col=c, k'=o
        int nt = rem >> 7, ks = (rem >> 6) & 1, l = rem & 63;
        int cc = (l & 15) + 16 * nt, ob = (l >> 4) * 8 + 32 * ks;
        #pragma unroll
        for (int j = 0; j < 8; ++j) {
            float a = (float)(((ob + j) * cc) & 63) * (TWO_PI / 64.f);
            re[j] = cosf(a); im[j] = sinf(a);
        }
    } else {                   // G128 inv: exp(+2pi i w u/128) / 8192, row=w, k=u
        int mt = rem >> 6, l = rem & 63;
        int w = (l & 15) + 16 * mt, ub = (l >> 4) * 8;
        #pragma unroll
        for (int j = 0; j < 8; ++j) {
            float a = (float)((w * (ub + j)) & 127) * (TWO_PI / 128.f);
            re[j] = cosf(a) * 0.0001220703125f;  // exact 2^-13, lossless in bf16
            im[j] = sinf(a) * 0.0001220703125f;
        }
    }
    ushort_t* dst = tabs + (size_t)e * 16;
    #pragma unroll
    for (int j = 0; j < 8; ++j) { dst[j] = f2bf(re[j]); dst[8 + j] = f2bf(im[j]); }
}

// ---------------------------------------------------------------------------
// K1: per (b, h<32). M1 = F128trunc . x  (32x64 cplx), X = M1 . G64fwd.
// X routed through LDS -> coalesced short8 stores to ws [h][u][comp][b][k].
// ---------------------------------------------------------------------------
__global__ __launch_bounds__(512) void k1_fwd(
    const float* __restrict__ x, const char* __restrict__ tabs, ushort_t* __restrict__ XY)
{
    const int b = blockIdx.x, h = blockIdx.y;
    const int tid = threadIdx.x, lane = tid & 63, wv = tid >> 6;
    constexpr int SXT  = 0;            // x^T bf16 [c64][w128], stride 272B; reused for X-out
    constexpr int M1RE = 17408;        // [u32][c64+pad], stride 144B
    constexpr int M1IM = 17408 + 4608;
    __shared__ __align__(16) char sm[26624];

    // load x slice (float4) + transpose -> sxT[c][w] bf16
    const float* xs = x + ((size_t)(b * NHt + h)) * (NWd * NC);
    #pragma unroll
    for (int i = 0; i < 4; ++i) {
        int idx = tid + 512 * i;               // 0..2047 float4s
        int w = idx >> 4, c4 = (idx & 15) * 4;
        f32x4 v = *reinterpret_cast<const f32x4*>(xs + w * 64 + c4);
        #pragma unroll
        for (int j = 0; j < 4; ++j)
            *(ushort_t*)(sm + SXT + (c4 + j) * 272 + w * 2) = f2bf(v[j]);
    }
    __syncthreads();

    const int mt = wv >> 2, nt = wv & 3;
    // stage 1: M1[u,c] = sum_w F[u,w] x[w,c]
    f32x4 m1r = {0.f,0.f,0.f,0.f}, m1i = {0.f,0.f,0.f,0.f};
    #pragma unroll
    for (int ks = 0; ks < 4; ++ks) {
        short8 bfrag = *reinterpret_cast<const short8*>(
            sm + SXT + ((lane & 15) + 16 * nt) * 272 + (lane >> 4) * 16 + 64 * ks);
        const char* t1 = tabs + TAB_T1 + (((mt * 4 + ks) * 64 + lane) * 32);
        short8 are = *reinterpret_cast<const short8*>(t1);
        short8 aim = *reinterpret_cast<const short8*>(t1 + 16);
        m1r = MFMA(are, bfrag, m1r);
        m1i = MFMA(aim, bfrag, m1i);
    }
    #pragma unroll
    for (int r = 0; r < 4; ++r) {
        int u = (lane >> 4) * 4 + r + 16 * mt;
        int c = (lane & 15) + 16 * nt;
        *(ushort_t*)(sm + M1RE + u * 144 + c * 2) = f2bf(m1r[r]);
        *(ushort_t*)(sm + M1IM + u * 144 + c * 2) = f2bf(m1i[r]);
    }
    __syncthreads();

    // stage 2: X[u,k] = sum_c M1[u,c] G64f[c,k]; fragments -> LDS [comp][u][k]
    f32x4 xP = {0.f,0.f,0.f,0.f}, xQ = {0.f,0.f,0.f,0.f}, xI = {0.f,0.f,0.f,0.f};
    #pragma unroll
    for (int ks = 0; ks < 2; ++ks) {
        short8 are = *reinterpret_cast<const short8*>(
            sm + M1RE + ((lane & 15) + 16 * mt) * 144 + (lane >> 4) * 16 + 64 * ks);
        short8 aim = *reinterpret_cast<const short8*>(
            sm + M1IM + ((lane & 15) + 16 * mt) * 144 + (lane >> 4) * 16 + 64 * ks);
        const char* t2 = tabs + TAB_T2 + (((nt * 2 + ks) * 64 + lane) * 32);
        short8 bre = *reinterpret_cast<const short8*>(t2);
        short8 bim = *reinterpret_cast<const short8*>(t2 + 16);
        xP = MFMA(are, bre, xP);
        xQ = MFMA(aim, bim, xQ);
        xI = MFMA(are, bim, xI);
        xI = MFMA(aim, bre, xI);
    }
    #pragma unroll
    for (int r = 0; r < 4; ++r) {
        int u = (lane >> 4) * 4 + r + 16 * mt;
        int k = (lane & 15) + 16 * nt;
        *(ushort_t*)(sm + SXT + 0    + u * 128 + k * 2) = f2bf(xP[r] - xQ[r]);
        *(ushort_t*)(sm + SXT + 4096 + u * 128 + k * 2) = f2bf(xI[r]);
    }
    __syncthreads();

    // coalesced X store: thread -> (u, comp, k8)
    {
        int u = tid >> 4, comp = (tid >> 3) & 1, k8 = (tid & 7) * 8;
        short8 v = *reinterpret_cast<const short8*>(sm + SXT + comp * 4096 + u * 128 + k8 * 2);
        size_t hu = (size_t)(h * 32 + u);
        *reinterpret_cast<short8*>(XY + ((hu * 2 + comp) * 32 + b) * 64 + k8) = v;
    }
}

// ---------------------------------------------------------------------------
// K2: per (h, u). Y[b,o] = sum_k X[b,k] W[h,u,k,o] — b-batched so W is read
// from HBM exactly once. In-place X->Y in ws, coalesced via LDS.
// ---------------------------------------------------------------------------
__global__ __launch_bounds__(256) void k2_mix(
    const float* __restrict__ wre, const float* __restrict__ wim, ushort_t* __restrict__ XY)
{
    const int h = blockIdx.x, u = blockIdx.y;
    const int tid = threadIdx.x, lane = tid & 63, wv = tid >> 6;   // 4 waves
    constexpr int XRE = 0, XIM = 4608, WTR = 9216, WTI = 18432;    // strides 144B
    __shared__ __align__(16) char sm[27648];
    const size_t hu = (size_t)(h * 32 + u);

    #pragma unroll
    for (int it = 0; it < 2; ++it) {        // stage X[b][k] (both comps)
        int row = (tid >> 3) + 32 * it;
        int comp = row >> 5, bb = row & 31, k8 = (tid & 7) * 8;
        short8 v = *reinterpret_cast<const short8*>(XY + ((hu * 2 + comp) * 32 + bb) * 64 + k8);
        *reinterpret_cast<short8*>(sm + (comp ? XIM : XRE) + bb * 144 + k8 * 2) = v;
    }
    const float* wr = wre + hu * 4096;      // transpose W -> WT[o][k] bf16 (float4 nt loads)
    const float* wi = wim + hu * 4096;
    #pragma unroll
    for (int i = 0; i < 4; ++i) {
        int idx = tid + 256 * i;            // 0..1023
        int k = idx >> 4, o4 = (idx & 15) * 4;
        f32x4 vr = __builtin_nontemporal_load(reinterpret_cast<const f32x4*>(wr + k * 64 + o4));
        f32x4 vi = __builtin_nontemporal_load(reinterpret_cast<const f32x4*>(wi + k * 64 + o4));
        #pragma unroll
        for (int j = 0; j < 4; ++j) {
            *(ushort_t*)(sm + WTR + (o4 + j) * 144 + k * 2) = f2bf(vr[j]);
            *(ushort_t*)(sm + WTI + (o4 + j) * 144 + k * 2) = f2bf(vi[j]);
        }
    }
    __syncthreads();

    const int mt = wv >> 1;
    f32x4 yRe[2], yIm[2];
    #pragma unroll
    for (int half = 0; half < 2; ++half) {
        const int nt = (wv & 1) * 2 + half;
        f32x4 yP = {0.f,0.f,0.f,0.f}, yQ = {0.f,0.f,0.f,0.f}, yI = {0.f,0.f,0.f,0.f};
        #pragma unroll
        for (int ks = 0; ks < 2; ++ks) {
            short8 are = *reinterpret_cast<const short8*>(
                sm + XRE + ((lane & 15) + 16 * mt) * 144 + (lane >> 4) * 16 + 64 * ks);
            short8 aim = *reinterpret_cast<const short8*>(
                sm + XIM + ((lane & 15) + 16 * mt) * 144 + (lane >> 4) * 16 + 64 * ks);
            short8 bre = *reinterpret_cast<const short8*>(
                sm + WTR + ((lane & 15) + 16 * nt) * 144 + (lane >> 4) * 16 + 64 * ks);
            short8 bim = *reinterpret_cast<const short8*>(
                sm + WTI + ((lane & 15) + 16 * nt) * 144 + (lane >> 4) * 16 + 64 * ks);
            yP = MFMA(are, bre, yP); yQ = MFMA(aim, bim, yQ);
            yI = MFMA(are, bim, yI); yI = MFMA(aim, bre, yI);
        }
        #pragma unroll
        for (int r = 0; r < 4; ++r) { yRe[half][r] = yP[r] - yQ[r]; yIm[half][r] = yI[r]; }
    }
    __syncthreads();   // X region dead; reuse as Y-out [comp][b][o] bf16

    #pragma unroll
    for (int half = 0; half < 2; ++half) {
        const int nt = (wv & 1) * 2 + half;
        #pragma unroll
        for (int r = 0; r < 4; ++r) {
            int bb = (lane >> 4) * 4 + r + 16 * mt;
            int o = (lane & 15) + 16 * nt;
            *(ushort_t*)(sm + 0    + bb * 128 + o * 2) = f2bf(yRe[half][r]);
            *(ushort_t*)(sm + 4096 + bb * 128 + o * 2) = f2bf(yIm[half][r]);
        }
    }
    __syncthreads();

    #pragma unroll
    for (int it = 0; it < 2; ++it) {        // coalesced Y store: 8 KB contiguous
        int flat = tid + 256 * it;          // (comp,b,o8) in global order
        short8 v = *reinterpret_cast<const short8*>(sm + flat * 16);
        *reinterpret_cast<short8*>(XY + hu * 4096 + flat * 8) = v;
    }
}

// ---------------------------------------------------------------------------
// K3: per (b, h). h<32: S = Y.G64inv, spec = Re(G128inv.S)/8192 (scale in tab).
// All h: conv (x bf16) + bias + relu + store.
// ---------------------------------------------------------------------------
__global__ __launch_bounds__(512) void k3_inv(
    const float* __restrict__ x, const float* __restrict__ cw, const float* __restrict__ cb,
    const char* __restrict__ tabs, const ushort_t* __restrict__ XY, float* __restrict__ out)
{
    const int b = blockIdx.x, h = blockIdx.y;
    const int tid = threadIdx.x, lane = tid & 63, wv = tid >> 6;
    constexpr int ST_RE = 0, ST_IM = 5120;            // S^T [c64][u32+pad], stride 80B
    constexpr int YRE = 10240, YIM = 14848;           // [u32][o64+pad], stride 144B
    constexpr int XB  = 10240;                        // [w128][c64+pad], stride 144B (reuses Y)
    constexpr int CWT = 28672;                        // [o64][i64+pad], stride 144B
    constexpr int SCB = 37888;                        // bias f32[64]
    __shared__ __align__(16) char sm[38144];

    if (h < MX) {
        {   // stage Y -> LDS
            int u = tid >> 4, comp = (tid >> 3) & 1, o8 = (tid & 7) * 8;
            size_t hu = (size_t)(h * 32 + u);
            short8 v = *reinterpret_cast<const short8*>(XY + ((hu * 2 + comp) * 32 + b) * 64 + o8);
            *reinterpret_cast<short8*>(sm + (comp ? YIM : YRE) + u * 144 + o8 * 2) = v;
        }
        __syncthreads();
        // stage 4: S[u,c] = sum_o Y[u,o] G64inv[o,c]; write S transposed [c][u]
        const int mt = wv >> 2, nt = wv & 3;
        f32x4 sP = {0.f,0.f,0.f,0.f}, sQ = {0.f,0.f,0.f,0.f}, sI = {0.f,0.f,0.f,0.f};
        #pragma unroll
        for (int ks = 0; ks < 2; ++ks) {
            short8 are = *reinterpret_cast<const short8*>(
                sm + YRE + ((lane & 15) + 16 * mt) * 144 + (lane >> 4) * 16 + 64 * ks);
            short8 aim = *reinterpret_cast<const short8*>(
                sm + YIM + ((lane & 15) + 16 * mt) * 144 + (lane >> 4) * 16 + 64 * ks);
            const char* t3 = tabs + TAB_T3 + (((nt * 2 + ks) * 64 + lane) * 32);
            short8 bre = *reinterpret_cast<const short8*>(t3);
            short8 bim = *reinterpret_cast<const short8*>(t3 + 16);
            sP = MFMA(are, bre, sP); sQ = MFMA(aim, bim, sQ);
            sI = MFMA(are, bim, sI); sI = MFMA(aim, bre, sI);
        }
        #pragma unroll
        for (int r = 0; r < 4; ++r) {
            int u = (lane >> 4) * 4 + r + 16 * mt;
            int c = (lane & 15) + 16 * nt;
            *(ushort_t*)(sm + ST_RE + c * 80 + u * 2) = f2bf(sP[r] - sQ[r]);
            *(ushort_t*)(sm + ST_IM + c * 80 + u * 2) = f2bf(sI[r]);
        }
    }
    __syncthreads();

    // stage x (bf16), conv_w^T, bias
    const float* xs = x + ((size_t)(b * NHt + h)) * (NWd * NC);
    #pragma unroll
    for (int i = 0; i < 4; ++i) {
        int idx = tid + 512 * i;
        int w = idx >> 4, c4 = (idx & 15) * 4;
        f32x4 v = __builtin_nontemporal_load(reinterpret_cast<const f32x4*>(xs + w * 64 + c4));
        ushort_t h0 = f2bf(v[0]), h1 = f2bf(v[1]), h2 = f2bf(v[2]), h3 = f2bf(v[3]);
        *(unsigned int*)(sm + XB + w * 144 + c4 * 2)     = (unsigned)h0 | ((unsigned)h1 << 16);
        *(unsigned int*)(sm + XB + w * 144 + c4 * 2 + 4) = (unsigned)h2 | ((unsigned)h3 << 16);
    }
    #pragma unroll
    for (int i = 0; i < 2; ++i) {
        int ii = (tid >> 4) + 32 * i;
        #pragma unroll
        for (int j = 0; j < 4; ++j) {
            int o = (tid & 15) + 16 * j;
            *(ushort_t*)(sm + CWT + o * 144 + ii * 2) = f2bf(cw[ii * 64 + o]);
        }
    }
    if (tid < 64) ((float*)(sm + SCB))[tid] = cb[tid];
    __syncthreads();

    short8 gre = {}, gim = {};
    if (h < MX) {
        const char* t4 = tabs + TAB_T4 + ((wv * 64 + lane) * 32);
        gre = *reinterpret_cast<const short8*>(t4);
        gim = *reinterpret_cast<const short8*>(t4 + 16);
    }
    float* orow = out + ((size_t)(b * NHt + h)) * (NWd * NC);
    #pragma unroll
    for (int nt = 0; nt < 4; ++nt) {
        f32x4 acc = {0.f,0.f,0.f,0.f};     // conv accumulator
        #pragma unroll
        for (int ks = 0; ks < 2; ++ks) {
            short8 ah = *reinterpret_cast<const short8*>(
                sm + XB + ((lane & 15) + 16 * wv) * 144 + (lane >> 4) * 16 + 64 * ks);
            short8 bw = *reinterpret_cast<const short8*>(
                sm + CWT + ((lane & 15) + 16 * nt) * 144 + (lane >> 4) * 16 + 64 * ks);
            acc = MFMA(ah, bw, acc);
        }
        f32x4 sp = {0.f,0.f,0.f,0.f}, sq = {0.f,0.f,0.f,0.f};
        if (h < MX) {   // stage 5: spec = Re(G128inv . S), K=32 single step
            short8 bre = *reinterpret_cast<const short8*>(
                sm + ST_RE + ((lane & 15) + 16 * nt) * 80 + (lane >> 4) * 16);
            short8 bim = *reinterpret_cast<const short8*>(
                sm + ST_IM + ((lane & 15) + 16 * nt) * 80 + (lane >> 4) * 16);
            sp = MFMA(gre, bre, sp);
            sq = MFMA(gim, bim, sq);
        }
        #pragma unroll
        for (int r = 0; r < 4; ++r) {
            int w = (lane >> 4) * 4 + r + 16 * wv;
            int c = (lane & 15) + 16 * nt;
            float v = acc[r] + ((const float*)(sm + SCB))[c];
            if (h < MX) v += sp[r] - sq[r];            // 1/8192 folded into T4
            orow[w * 64 + c] = fmaxf(v, 0.0f);
        }
    }
}

extern "C" void kernel_launch(void* const* d_in, const int* in_sizes, int n_in,
                              void* d_out, int out_size, void* d_ws, size_t ws_size,
                              hipStream_t stream) {
    const float* x      = (const float*)d_in[0];
    const float* w_real = (const float*)d_in[1];
    const float* w_imag = (const float*)d_in[2];
    const float* conv_w = (const float*)d_in[3];
    const float* conv_b = (const float*)d_in[4];
    float* out = (float*)d_out;

    ushort_t* tabs = (ushort_t*)d_ws;
    ushort_t* XY   = (ushort_t*)((char*)d_ws + XY_OFF);

    k0_tables<<<8, 256, 0, stream>>>(tabs);
    k1_fwd<<<dim3(NB, MX), 512, 0, stream>>>(x, (const char*)d_ws, XY);
    k2_mix<<<dim3(MX, 32), 256, 0, stream>>>(w_real, w_imag, XY);
    k3_inv<<<dim3(NB, NHt), 512, 0, stream>>>(x, conv_w, conv_b,
                                              (const char*)d_ws, XY, out);
}

// Round 4
// 83.915 us; speedup vs baseline: 5.4797x; 1.0077x over previous
//
#include <hip/hip_runtime.h>

typedef __attribute__((ext_vector_type(8))) short short8;
typedef __attribute__((ext_vector_type(4))) short bf16x4;
typedef __attribute__((ext_vector_type(4))) float f32x4;
typedef unsigned short ushort_t;

#define MFMA(a, b, c) __builtin_amdgcn_mfma_f32_16x16x32_bf16((a), (b), (c), 0, 0, 0)

constexpr int NB = 32, NHt = 128, NWd = 128, NC = 64, MX = 32;
constexpr float TWO_PI = 6.28318530717958647692f;

// workspace layout (64 KB tables + 8 MiB X/Y buffer)
constexpr size_t TAB_T1 = 0;      // K1 stage1 A: F128 fwd  [mt2][ks4][lane64][re8,im8]
constexpr size_t TAB_T2 = 16384;  // K1 stage2 B: G64  fwd  [nt4][ks2][lane64][re8,im8]
constexpr size_t TAB_T3 = 32768;  // K3 stage4 B: G64  inv  [nt4][ks2][lane64][re8,im8]
constexpr size_t TAB_T4 = 49152;  // K3 stage5 A: G128 inv  [mt8][lane64][re8,im8] (x 1/8192)
constexpr size_t XY_OFF = 65536;  // X then Y in-place: bf16 [h32][u32][comp2][b32][k64]

__device__ inline ushort_t f2bf(float f) {
    union { float f; unsigned int u; } v; v.f = f;
    unsigned int r = v.u + 0x7FFFu + ((v.u >> 16) & 1u);   // RTN-even
    return (ushort_t)(r >> 16);
}
// row-dependent XOR swizzle (bits 4-5): breaks the {0,16} bank pattern of
// power-of-two-ish row strides; 16B-granular so ds_read_b128 stays aligned.
__device__ inline int sxor(int row) { return ((row >> 3) & 3) << 4; }

// ---------------------------------------------------------------------------
// K0: twiddle fragment tables in exact MFMA A/B lane layout.
// A/B frag: row/col = (lane&15)+16*tile, k = (lane>>4)*8 + j (+32*ks).
// ---------------------------------------------------------------------------
__global__ __launch_bounds__(256) void k0_tables(ushort_t* __restrict__ tabs)
{
    int e = blockIdx.x * 256 + threadIdx.x;   // 0..2047
    int tab = e >> 9, rem = e & 511;
    float re[8], im[8];
    if (tab == 0) {            // F128 fwd: exp(-2pi i u w/128)
        int mt = rem >> 8, ks = (rem >> 6) & 3, l = rem & 63;
        int uu = (l & 15) + 16 * mt, wb = (l >> 4) * 8 + 32 * ks;
        #pragma unroll
        for (int j = 0; j < 8; ++j) {
            float a = (float)((uu * (wb + j)) & 127) * (TWO_PI / 128.f);
            re[j] = cosf(a); im[j] = -sinf(a);
        }
    } else if (tab == 1) {     // G64 fwd: exp(-2pi i k c/64), col=k, k'=c
        int nt = rem >> 7, ks = (rem >> 6) & 1, l = rem & 63;
        int kk = (l & 15) + 16 * nt, cb2 = (l >> 4) * 8 + 32 * ks;
        #pragma unroll
        for (int j = 0; j < 8; ++j) {
            float a = (float)((kk * (cb2 + j)) & 63) * (TWO_PI / 64.f);
            re[j] = cosf(a); im[j] = -sinf(a);
        }
    } else if (tab == 2) {     // G64 inv: exp(+2pi i o c/64), col=c, k'=o
        int nt = rem >> 7, ks = (rem >> 6) & 1, l = rem & 63;
        int cc = (l & 15) + 16 * nt, ob = (l >> 4) * 8 + 32 * ks;
        #pragma unroll
        for (int j = 0; j < 8; ++j) {
            float a = (float)(((ob + j) * cc) & 63) * (TWO_PI / 64.f);
            re[j] = cosf(a); im[j] = sinf(a);
        }
    } else {                   // G128 inv: exp(+2pi i w u/128) / 8192, row=w, k=u
        int mt = rem >> 6, l = rem & 63;
        int w = (l & 15) + 16 * mt, ub = (l >> 4) * 8;
        #pragma unroll
        for (int j = 0; j < 8; ++j) {
            float a = (float)((w * (ub + j)) & 127) * (TWO_PI / 128.f);
            re[j] = cosf(a) * 0.0001220703125f;  // exact 2^-13, lossless in bf16
            im[j] = sinf(a) * 0.0001220703125f;
        }
    }
    ushort_t* dst = tabs + (size_t)e * 16;
    #pragma unroll
    for (int j = 0; j < 8; ++j) { dst[j] = f2bf(re[j]); dst[8 + j] = f2bf(im[j]); }
}

// ---------------------------------------------------------------------------
// K1: per (b, h<32). M1 = F128trunc . x  (32x64 cplx), X = M1 . G64fwd.
// X routed through LDS -> coalesced short8 stores to ws [h][u][comp][b][k].
// sxT transpose writes/reads XOR-swizzled (8-way -> 2-way bank conflicts).
// ---------------------------------------------------------------------------
__global__ __launch_bounds__(512) void k1_fwd(
    const float* __restrict__ x, const char* __restrict__ tabs, ushort_t* __restrict__ XY)
{
    const int b = blockIdx.x, h = blockIdx.y;
    const int tid = threadIdx.x, lane = tid & 63, wv = tid >> 6;
    constexpr int SXT  = 0;            // x^T bf16 [c64][w128], stride 272B; reused for X-out
    constexpr int M1RE = 17408;        // [u32][c64+pad], stride 144B
    constexpr int M1IM = 17408 + 4608;
    __shared__ __align__(16) char sm[26624];

    // load x slice (float4) + transpose -> sxT[c][w] bf16 (swizzled)
    const float* xs = x + ((size_t)(b * NHt + h)) * (NWd * NC);
    #pragma unroll
    for (int i = 0; i < 4; ++i) {
        int idx = tid + 512 * i;               // 0..2047 float4s
        int w = idx >> 4, c4 = (idx & 15) * 4;
        f32x4 v = *reinterpret_cast<const f32x4*>(xs + w * 64 + c4);
        #pragma unroll
        for (int j = 0; j < 4; ++j)
            *(ushort_t*)(sm + SXT + (c4 + j) * 272 + ((w * 2) ^ sxor(c4 + j))) = f2bf(v[j]);
    }
    __syncthreads();

    const int mt = wv >> 2, nt = wv & 3;
    // stage 1: M1[u,c] = sum_w F[u,w] x[w,c]
    f32x4 m1r = {0.f,0.f,0.f,0.f}, m1i = {0.f,0.f,0.f,0.f};
    const int cc = (lane & 15) + 16 * nt;
    #pragma unroll
    for (int ks = 0; ks < 4; ++ks) {
        short8 bfrag = *reinterpret_cast<const short8*>(
            sm + SXT + cc * 272 + (((lane >> 4) * 16 + 64 * ks) ^ sxor(cc)));
        const char* t1 = tabs + TAB_T1 + (((mt * 4 + ks) * 64 + lane) * 32);
        short8 are = *reinterpret_cast<const short8*>(t1);
        short8 aim = *reinterpret_cast<const short8*>(t1 + 16);
        m1r = MFMA(are, bfrag, m1r);
        m1i = MFMA(aim, bfrag, m1i);
    }
    #pragma unroll
    for (int r = 0; r < 4; ++r) {
        int u = (lane >> 4) * 4 + r + 16 * mt;
        int c = (lane & 15) + 16 * nt;
        *(ushort_t*)(sm + M1RE + u * 144 + c * 2) = f2bf(m1r[r]);
        *(ushort_t*)(sm + M1IM + u * 144 + c * 2) = f2bf(m1i[r]);
    }
    __syncthreads();

    // stage 2: X[u,k] = sum_c M1[u,c] G64f[c,k]; fragments -> LDS [comp][u][k]
    f32x4 xP = {0.f,0.f,0.f,0.f}, xQ = {0.f,0.f,0.f,0.f}, xI = {0.f,0.f,0.f,0.f};
    #pragma unroll
    for (int ks = 0; ks < 2; ++ks) {
        short8 are = *reinterpret_cast<const short8*>(
            sm + M1RE + ((lane & 15) + 16 * mt) * 144 + (lane >> 4) * 16 + 64 * ks);
        short8 aim = *reinterpret_cast<const short8*>(
            sm + M1IM + ((lane & 15) + 16 * mt) * 144 + (lane >> 4) * 16 + 64 * ks);
        const char* t2 = tabs + TAB_T2 + (((nt * 2 + ks) * 64 + lane) * 32);
        short8 bre = *reinterpret_cast<const short8*>(t2);
        short8 bim = *reinterpret_cast<const short8*>(t2 + 16);
        xP = MFMA(are, bre, xP);
        xQ = MFMA(aim, bim, xQ);
        xI = MFMA(are, bim, xI);
        xI = MFMA(aim, bre, xI);
    }
    #pragma unroll
    for (int r = 0; r < 4; ++r) {
        int u = (lane >> 4) * 4 + r + 16 * mt;
        int k = (lane & 15) + 16 * nt;
        *(ushort_t*)(sm + SXT + 0    + u * 128 + k * 2) = f2bf(xP[r] - xQ[r]);
        *(ushort_t*)(sm + SXT + 4096 + u * 128 + k * 2) = f2bf(xI[r]);
    }
    __syncthreads();

    // coalesced X store: thread -> (u, comp, k8)
    {
        int u = tid >> 4, comp = (tid >> 3) & 1, k8 = (tid & 7) * 8;
        short8 v = *reinterpret_cast<const short8*>(sm + SXT + comp * 4096 + u * 128 + k8 * 2);
        size_t hu = (size_t)(h * 32 + u);
        *reinterpret_cast<short8*>(XY + ((hu * 2 + comp) * 32 + b) * 64 + k8) = v;
    }
}

// ---------------------------------------------------------------------------
// K2: per (h, u). Y[b,o] = sum_k X[b,k] W[h,u,k,o] — b-batched so W is read
// from HBM exactly once. W-transpose writes/reads XOR-swizzled.
// ---------------------------------------------------------------------------
__global__ __launch_bounds__(256) void k2_mix(
    const float* __restrict__ wre, const float* __restrict__ wim, ushort_t* __restrict__ XY)
{
    const int h = blockIdx.x, u = blockIdx.y;
    const int tid = threadIdx.x, lane = tid & 63, wv = tid >> 6;   // 4 waves
    constexpr int XRE = 0, XIM = 4608, WTR = 9216, WTI = 18432;    // strides 144B
    __shared__ __align__(16) char sm[27648];
    const size_t hu = (size_t)(h * 32 + u);

    #pragma unroll
    for (int it = 0; it < 2; ++it) {        // stage X[b][k] (both comps)
        int row = (tid >> 3) + 32 * it;
        int comp = row >> 5, bb = row & 31, k8 = (tid & 7) * 8;
        short8 v = *reinterpret_cast<const short8*>(XY + ((hu * 2 + comp) * 32 + bb) * 64 + k8);
        *reinterpret_cast<short8*>(sm + (comp ? XIM : XRE) + bb * 144 + k8 * 2) = v;
    }
    const float* wr = wre + hu * 4096;      // transpose W -> WT[o][k] bf16 (swizzled)
    const float* wi = wim + hu * 4096;
    #pragma unroll
    for (int i = 0; i < 4; ++i) {
        int idx = tid + 256 * i;            // 0..1023
        int k = idx >> 4, o4 = (idx & 15) * 4;
        f32x4 vr = __builtin_nontemporal_load(reinterpret_cast<const f32x4*>(wr + k * 64 + o4));
        f32x4 vi = __builtin_nontemporal_load(reinterpret_cast<const f32x4*>(wi + k * 64 + o4));
        #pragma unroll
        for (int j = 0; j < 4; ++j) {
            int o = o4 + j, koff = (k * 2) ^ sxor(o);
            *(ushort_t*)(sm + WTR + o * 144 + koff) = f2bf(vr[j]);
            *(ushort_t*)(sm + WTI + o * 144 + koff) = f2bf(vi[j]);
        }
    }
    __syncthreads();

    const int mt = wv >> 1;
    f32x4 yRe[2], yIm[2];
    #pragma unroll
    for (int half = 0; half < 2; ++half) {
        const int nt = (wv & 1) * 2 + half;
        const int oo = (lane & 15) + 16 * nt;
        f32x4 yP = {0.f,0.f,0.f,0.f}, yQ = {0.f,0.f,0.f,0.f}, yI = {0.f,0.f,0.f,0.f};
        #pragma unroll
        for (int ks = 0; ks < 2; ++ks) {
            int woff = ((lane >> 4) * 16 + 64 * ks) ^ sxor(oo);
            short8 are = *reinterpret_cast<const short8*>(
                sm + XRE + ((lane & 15) + 16 * mt) * 144 + (lane >> 4) * 16 + 64 * ks);
            short8 aim = *reinterpret_cast<const short8*>(
                sm + XIM + ((lane & 15) + 16 * mt) * 144 + (lane >> 4) * 16 + 64 * ks);
            short8 bre = *reinterpret_cast<const short8*>(sm + WTR + oo * 144 + woff);
            short8 bim = *reinterpret_cast<const short8*>(sm + WTI + oo * 144 + woff);
            yP = MFMA(are, bre, yP); yQ = MFMA(aim, bim, yQ);
            yI = MFMA(are, bim, yI); yI = MFMA(aim, bre, yI);
        }
        #pragma unroll
        for (int r = 0; r < 4; ++r) { yRe[half][r] = yP[r] - yQ[r]; yIm[half][r] = yI[r]; }
    }
    __syncthreads();   // X region dead; reuse as Y-out [comp][b][o] bf16

    #pragma unroll
    for (int half = 0; half < 2; ++half) {
        const int nt = (wv & 1) * 2 + half;
        #pragma unroll
        for (int r = 0; r < 4; ++r) {
            int bb = (lane >> 4) * 4 + r + 16 * mt;
            int o = (lane & 15) + 16 * nt;
            *(ushort_t*)(sm + 0    + bb * 128 + o * 2) = f2bf(yRe[half][r]);
            *(ushort_t*)(sm + 4096 + bb * 128 + o * 2) = f2bf(yIm[half][r]);
        }
    }
    __syncthreads();

    #pragma unroll
    for (int it = 0; it < 2; ++it) {        // coalesced Y store: 8 KB contiguous
        int flat = tid + 256 * it;          // (comp,b,o8) in global order
        short8 v = *reinterpret_cast<const short8*>(sm + flat * 16);
        *reinterpret_cast<short8*>(XY + hu * 4096 + flat * 8) = v;
    }
}

// ---------------------------------------------------------------------------
// K3: per (b, h). h<32: S = Y.G64inv, spec = Re(G128inv.S) (1/8192 in table).
// All h: conv (x bf16) + bias + relu. Output staged in padded LDS buffer ->
// fully coalesced nontemporal dwordx4 stores. Y decoupled from XB so x
// staging overlaps the spectral phase.
// ---------------------------------------------------------------------------
__global__ __launch_bounds__(512, 4) void k3_inv(
    const float* __restrict__ x, const float* __restrict__ cw, const float* __restrict__ cb,
    const char* __restrict__ tabs, const ushort_t* __restrict__ XY, float* __restrict__ out)
{
    const int b = blockIdx.x, h = blockIdx.y;
    const int tid = threadIdx.x, lane = tid & 63, wv = tid >> 6;
    constexpr int ST_RE = 0, ST_IM = 5120;   // S^T [c64][u32+pad], stride 80B
    constexpr int XB   = 10240;              // x bf16 [w128][c64+pad], stride 144B
    constexpr int CWT  = 28672;              // conv_w^T [o64][i64+pad], stride 144B
    constexpr int SCB  = 37888;              // bias f32[64]
    constexpr int OUTB = 38144;              // out f32 [w128][c64+4pad], stride 272B
    constexpr int YRE  = 38144;              // Y staging inside OUTB (dead by store time)
    constexpr int YIM  = 38144 + 4608;       // strides 144B
    __shared__ __align__(16) char sm[72960];

    // ---- issue all global loads up front ----
    const float* xs = x + ((size_t)(b * NHt + h)) * (NWd * NC);
    f32x4 xv[4];
    #pragma unroll
    for (int i = 0; i < 4; ++i) {
        int idx = tid + 512 * i;
        int w = idx >> 4, c4 = (idx & 15) * 4;
        xv[i] = __builtin_nontemporal_load(reinterpret_cast<const f32x4*>(xs + w * 64 + c4));
    }
    short8 yv = {}, gre = {}, gim = {};
    if (h < MX) {
        int u = tid >> 4, comp = (tid >> 3) & 1, o8 = (tid & 7) * 8;
        size_t hu = (size_t)(h * 32 + u);
        yv = *reinterpret_cast<const short8*>(XY + ((hu * 2 + comp) * 32 + b) * 64 + o8);
        const char* t4 = tabs + TAB_T4 + ((wv * 64 + lane) * 32);
        gre = *reinterpret_cast<const short8*>(t4);
        gim = *reinterpret_cast<const short8*>(t4 + 16);
    }

    // ---- stage x (bf16, packed 8B writes), conv_w^T, bias ----
    #pragma unroll
    for (int i = 0; i < 4; ++i) {
        int idx = tid + 512 * i;
        int w = idx >> 4, c4 = (idx & 15) * 4;
        bf16x4 pk = { (short)f2bf(xv[i][0]), (short)f2bf(xv[i][1]),
                      (short)f2bf(xv[i][2]), (short)f2bf(xv[i][3]) };
        *reinterpret_cast<bf16x4*>(sm + XB + w * 144 + c4 * 2) = pk;
    }
    #pragma unroll
    for (int i = 0; i < 2; ++i) {
        int ii = (tid >> 4) + 32 * i;
        #pragma unroll
        for (int j = 0; j < 4; ++j) {
            int o = (tid & 15) + 16 * j;
            *(ushort_t*)(sm + CWT + o * 144 + ii * 2) = f2bf(cw[ii * 64 + o]);
        }
    }
    if (tid < 64) ((float*)(sm + SCB))[tid] = cb[tid];

    if (h < MX) {
        {   // Y -> LDS (its own region; does not alias XB)
            int u = tid >> 4, comp = (tid >> 3) & 1, o8 = (tid & 7) * 8;
            *reinterpret_cast<short8*>(sm + (comp ? YIM : YRE) + u * 144 + o8 * 2) = yv;
        }
        __syncthreads();
        // stage 4: S[u,c] = sum_o Y[u,o] G64inv[o,c]; write S transposed [c][u]
        const int mt = wv >> 2, nt = wv & 3;
        f32x4 sP = {0.f,0.f,0.f,0.f}, sQ = {0.f,0.f,0.f,0.f}, sI = {0.f,0.f,0.f,0.f};
        #pragma unroll
        for (int ks = 0; ks < 2; ++ks) {
            short8 are = *reinterpret_cast<const short8*>(
                sm + YRE + ((lane & 15) + 16 * mt) * 144 + (lane >> 4) * 16 + 64 * ks);
            short8 aim = *reinterpret_cast<const short8*>(
                sm + YIM + ((lane & 15) + 16 * mt) * 144 + (lane >> 4) * 16 + 64 * ks);
            const char* t3 = tabs + TAB_T3 + (((nt * 2 + ks) * 64 + lane) * 32);
            short8 bre = *reinterpret_cast<const short8*>(t3);
            short8 bim = *reinterpret_cast<const short8*>(t3 + 16);
            sP = MFMA(are, bre, sP); sQ = MFMA(aim, bim, sQ);
            sI = MFMA(are, bim, sI); sI = MFMA(aim, bre, sI);
        }
        #pragma unroll
        for (int r = 0; r < 4; ++r) {
            int u = (lane >> 4) * 4 + r + 16 * mt;
            int c = (lane & 15) + 16 * nt;
            *(ushort_t*)(sm + ST_RE + c * 80 + u * 2) = f2bf(sP[r] - sQ[r]);
            *(ushort_t*)(sm + ST_IM + c * 80 + u * 2) = f2bf(sI[r]);
        }
    }
    __syncthreads();

    // ---- conv + spec MFMAs; stream results into padded LDS out buffer ----
    #pragma unroll
    for (int nt = 0; nt < 4; ++nt) {
        f32x4 acc = {0.f,0.f,0.f,0.f};
        #pragma unroll
        for (int ks = 0; ks < 2; ++ks) {
            short8 ah = *reinterpret_cast<const short8*>(
                sm + XB + ((lane & 15) + 16 * wv) * 144 + (lane >> 4) * 16 + 64 * ks);
            short8 bw = *reinterpret_cast<const short8*>(
                sm + CWT + ((lane & 15) + 16 * nt) * 144 + (lane >> 4) * 16 + 64 * ks);
            acc = MFMA(ah, bw, acc);
        }
        f32x4 sp = {0.f,0.f,0.f,0.f}, sq = {0.f,0.f,0.f,0.f};
        if (h < MX) {
            short8 bre = *reinterpret_cast<const short8*>(
                sm + ST_RE + ((lane & 15) + 16 * nt) * 80 + (lane >> 4) * 16);
            short8 bim = *reinterpret_cast<const short8*>(
                sm + ST_IM + ((lane & 15) + 16 * nt) * 80 + (lane >> 4) * 16);
            sp = MFMA(gre, bre, sp);
            sq = MFMA(gim, bim, sq);
        }
        #pragma unroll
        for (int r = 0; r < 4; ++r) {
            int w = (lane >> 4) * 4 + r + 16 * wv;
            int c = (lane & 15) + 16 * nt;
            float v = acc[r] + ((const float*)(sm + SCB))[c];
            if (h < MX) v += sp[r] - sq[r];            // 1/8192 folded into T4
            *(float*)(sm + OUTB + w * 272 + c * 4) = fmaxf(v, 0.0f);
        }
    }
    __syncthreads();

    // ---- fully coalesced nontemporal stores ----
    float* orow = out + ((size_t)(b * NHt + h)) * (NWd * NC);
    #pragma unroll
    for (int i = 0; i < 4; ++i) {
        int flat = tid + 512 * i;              // 0..2047 float4s
        int w = flat >> 4, c4 = (flat & 15) * 4;
        f32x4 v = *reinterpret_cast<const f32x4*>(sm + OUTB + w * 272 + c4 * 4);
        __builtin_nontemporal_store(v, reinterpret_cast<f32x4*>(orow + w * 64 + c4));
    }
}

extern "C" void kernel_launch(void* const* d_in, const int* in_sizes, int n_in,
                              void* d_out, int out_size, void* d_ws, size_t ws_size,
                              hipStream_t stream) {
    const float* x      = (const float*)d_in[0];
    const float* w_real = (const float*)d_in[1];
    const float* w_imag = (const float*)d_in[2];
    const float* conv_w = (const float*)d_in[3];
    const float* conv_b = (const float*)d_in[4];
    float* out = (float*)d_out;

    ushort_t* tabs = (ushort_t*)d_ws;
    ushort_t* XY   = (ushort_t*)((char*)d_ws + XY_OFF);

    k0_tables<<<8, 256, 0, stream>>>(tabs);
    k1_fwd<<<dim3(NB, MX), 512, 0, stream>>>(x, (const char*)d_ws, XY);
    k2_mix<<<dim3(MX, 32), 256, 0, stream>>>(w_real, w_imag, XY);
    k3_inv<<<dim3(NB, NHt), 512, 0, stream>>>(x, conv_w, conv_b,
                                              (const char*)d_ws, XY, out);
}